// Round 10
// baseline (397.079 us; speedup 1.0000x reference)
//
#include <hip/hip_runtime.h>
#include <math.h>

#define NUM_DRUG 50000
#define NUM_CELL 20000
#define NUM_TOT  (NUM_DRUG + NUM_CELL)
#define HDIM 128
#define NE 600000
#define NB 4096
#define LN_EPS 1e-5f
#define LDA 132   // padded LDS row (floats)

#define CELL_BLOCKS ((NUM_CELL + 31) / 32)   // 625
#define DRUG_BLOCKS ((NUM_DRUG + 31) / 32)   // 1563
#define AGG_BLOCKS  (NUM_TOT / 16)           // 4375 (exact)
#define CAST_BLOCKS (NUM_TOT * HDIM / 8 / 256)  // 4375
#define WCAST_BLOCKS 16                      // 2*128*128/8/256
#define HIST_BLOCKS ((2 * NE + 255) / 256)   // 4688
#define FILL_BLOCKS 2048                     // 8 partitions x 256 blocks

typedef unsigned short u16;
typedef unsigned int u32;

__device__ __forceinline__ float bflo(u32 u) { return __uint_as_float(u << 16); }
__device__ __forceinline__ float bfhi(u32 u) { return __uint_as_float(u & 0xFFFF0000u); }
__device__ __forceinline__ u32 f2bf1(float f) {
    u32 u = __float_as_uint(f);
    return (u + 0x7FFFu + ((u >> 16) & 1u)) >> 16;  // RNE
}
__device__ __forceinline__ u32 packbf(float lo, float hi) {
    return f2bf1(lo) | (f2bf1(hi) << 16);
}

#define ACC8(u) do { \
    a0 += bflo((u).x); a1 += bfhi((u).x); a2 += bflo((u).y); a3 += bfhi((u).y); \
    a4 += bflo((u).z); a5 += bfhi((u).z); a6 += bflo((u).w); a7 += bfhi((u).w); } while (0)

// ---------------------------------------------------------------------------
// prep: [0,CAST) cast emb fp32->bf16; [CAST,CAST+W) cast+transpose W -> bf16
// WT[k][c]; rest: histogram dst ids
// ---------------------------------------------------------------------------
__global__ void prep_kernel(const float* __restrict__ ed, const float* __restrict__ ec,
                            u16* __restrict__ e16d, u16* __restrict__ e16c,
                            const float* __restrict__ W_dt, const float* __restrict__ W_td,
                            u16* __restrict__ wtd, u16* __restrict__ wtt,
                            const int* __restrict__ dt_dst, const int* __restrict__ td_dst,
                            int* __restrict__ cnt_c, int* __restrict__ cnt_d) {
    if (blockIdx.x < CAST_BLOCKS) {
        const int ND8 = NUM_DRUG * HDIM / 8;
        int t = blockIdx.x * blockDim.x + threadIdx.x;
        const float4* src;
        u16* dst;
        int i;
        if (t < ND8) { src = (const float4*)ed; dst = e16d; i = t; }
        else { src = (const float4*)ec; dst = e16c; i = t - ND8; }
        float4 v0 = src[2 * i], v1 = src[2 * i + 1];
        uint4 o;
        o.x = packbf(v0.x, v0.y);
        o.y = packbf(v0.z, v0.w);
        o.z = packbf(v1.x, v1.y);
        o.w = packbf(v1.z, v1.w);
        ((uint4*)dst)[i] = o;
    } else if (blockIdx.x < CAST_BLOCKS + WCAST_BLOCKS) {
        int t = (blockIdx.x - CAST_BLOCKS) * blockDim.x + threadIdx.x;  // 0..4095
        const float* Wsrc = (t < 2048) ? W_dt : W_td;
        u16* Wdst = (t < 2048) ? wtd : wtt;
        const int i = (t & 2047) * 8;       // WT flat index base (k*128 + c)
        const int k = i >> 7;
        const int c0 = i & 127;
        __align__(16) u16 tmp[8];
#pragma unroll
        for (int j = 0; j < 8; ++j) tmp[j] = (u16)f2bf1(Wsrc[(size_t)(c0 + j) * HDIM + k]);
        *(uint4*)(Wdst + i) = *(const uint4*)tmp;
    } else {
        int t = (blockIdx.x - CAST_BLOCKS - WCAST_BLOCKS) * blockDim.x + threadIdx.x;
        if (t < NE) {
            atomicAdd(&cnt_c[dt_dst[t]], 1);
        } else if (t < 2 * NE) {
            atomicAdd(&cnt_d[td_dst[t - NE]], 1);
        }
    }
}

// ---------------------------------------------------------------------------
// single-block exclusive scan; writes rs (n+1) and cur (=rs copy)
// ---------------------------------------------------------------------------
__global__ void scan_kernel(const int* __restrict__ cnt0, int* __restrict__ rs0, int* __restrict__ cur0, int n0,
                            const int* __restrict__ cnt1, int* __restrict__ rs1, int* __restrict__ cur1, int n1) {
    const int* cnt = blockIdx.x ? cnt1 : cnt0;
    int* rs  = blockIdx.x ? rs1 : rs0;
    int* cur = blockIdx.x ? cur1 : cur0;
    int n = blockIdx.x ? n1 : n0;

    __shared__ int wsum[16];
    __shared__ int s_carry;
    const int tid = threadIdx.x;
    const int lane = tid & 63;
    const int w = tid >> 6;
    if (tid == 0) s_carry = 0;
    __syncthreads();

    for (int base = 0; base < n; base += 1024) {
        int v = (base + tid < n) ? cnt[base + tid] : 0;
        int x = v;
#pragma unroll
        for (int o = 1; o < 64; o <<= 1) {
            int y = __shfl_up(x, o);
            if (lane >= o) x += y;
        }
        if (lane == 63) wsum[w] = x;
        __syncthreads();
        if (w == 0 && lane < 16) {
            int y = wsum[lane];
#pragma unroll
            for (int o = 1; o < 16; o <<= 1) {
                int z = __shfl_up(y, o);
                if (lane >= o) y += z;
            }
            wsum[lane] = y;
        }
        __syncthreads();
        int total = wsum[15];
        int excl = s_carry + (w ? wsum[w - 1] : 0) + x - v;
        if (base + tid < n) { rs[base + tid] = excl; cur[base + tid] = excl; }
        __syncthreads();
        if (tid == 0) s_carry += total;
        __syncthreads();
    }
    if (tid == 0) rs[n] = s_carry;
}

// ---------------------------------------------------------------------------
// XCD-partitioned fill: partition p = blockIdx&7 owns dst ranges
// [p*2500,(p+1)*2500) cell / [p*6250,(p+1)*6250) drug. Each partition's CSR
// slice is contiguous (rs monotone) -> writes stay in one XCD's L2, evicted
// once. All blocks scan the full edge list (re-reads are LLC-hot).
// ---------------------------------------------------------------------------
__global__ __launch_bounds__(256, 8)
void fill_kernel(const int* __restrict__ dt_src, const int* __restrict__ dt_dst,
                 const int* __restrict__ td_src, const int* __restrict__ td_dst,
                 int* __restrict__ cur_c, int* __restrict__ cur_d,
                 u16* __restrict__ csr_dt, u16* __restrict__ csr_td) {
    const int p = blockIdx.x & 7;
    const int bsub = blockIdx.x >> 3;                 // 0..255
    const int stride = (FILL_BLOCKS >> 3) * 256;      // 65536
    const int base = bsub * 256 + threadIdx.x;
    const int clo = p * (NUM_CELL / 8);
    const int dlo = p * (NUM_DRUG / 8);

    for (int t = base; t < NE; t += stride) {
        const int d = dt_dst[t];
        if ((unsigned)(d - clo) < (unsigned)(NUM_CELL / 8)) {
            const int pos = atomicAdd(&cur_c[d], 1);
            csr_dt[pos] = (u16)dt_src[t];
        }
    }
    for (int t = base; t < NE; t += stride) {
        const int d = td_dst[t];
        if ((unsigned)(d - dlo) < (unsigned)(NUM_DRUG / 8)) {
            const int pos = atomicAdd(&cur_d[d], 1);
            csr_td[pos] = (u16)td_src[t];
        }
    }
}

// ---------------------------------------------------------------------------
// layer-1 gather: quarter-wave owns one dst row, unroll-4, zero LDS.
// Writes mean rows (bf16) into agg table: rows [0,NUM_CELL)=cell dst,
// [NUM_CELL,NUM_TOT)=drug dst.
// ---------------------------------------------------------------------------
__global__ __launch_bounds__(256, 8)
void agg_kernel(const u16* __restrict__ srcd, const u16* __restrict__ srcc,
                const u16* __restrict__ csr_dt, const int* __restrict__ rs_c,
                const u16* __restrict__ csr_td, const int* __restrict__ rs_d,
                u16* __restrict__ agg) {
    const int tid = threadIdx.x;
    const int lane = tid & 63;
    const int w = tid >> 6;
    const int q = lane >> 4;
    const int l16 = lane & 15;
    const int g = blockIdx.x * 16 + w * 4 + q;   // 0..NUM_TOT-1 (grid exact)

    const bool isCell = g < NUM_CELL;
    const u16* hsrc = isCell ? srcd : srcc;
    const u16* csr  = isCell ? csr_dt : csr_td;
    const int* rs   = isCell ? rs_c : rs_d;
    const int row   = isCell ? g : g - NUM_CELL;

    const int beg = rs[row];
    const int deg = rs[row + 1] - beg;
    const int last = (deg > 0) ? deg - 1 : 0;
    int dmax = deg;
    dmax = max(dmax, __shfl_xor(dmax, 16));
    dmax = max(dmax, __shfl_xor(dmax, 32));

    float a0 = 0.f, a1 = 0.f, a2 = 0.f, a3 = 0.f, a4 = 0.f, a5 = 0.f, a6 = 0.f, a7 = 0.f;
    int i = 0;
    for (; i + 3 < dmax; i += 4) {
        const int i0 = (i     < deg) ? i     : last;
        const int i1 = (i + 1 < deg) ? i + 1 : last;
        const int i2 = (i + 2 < deg) ? i + 2 : last;
        const int i3 = (i + 3 < deg) ? i + 3 : last;
        uint4 u0 = *((const uint4*)(hsrc + (size_t)csr[beg + i0] * HDIM) + l16);
        uint4 u1 = *((const uint4*)(hsrc + (size_t)csr[beg + i1] * HDIM) + l16);
        uint4 u2 = *((const uint4*)(hsrc + (size_t)csr[beg + i2] * HDIM) + l16);
        uint4 u3 = *((const uint4*)(hsrc + (size_t)csr[beg + i3] * HDIM) + l16);
        if (i     >= deg) { u0.x = u0.y = u0.z = u0.w = 0u; }
        if (i + 1 >= deg) { u1.x = u1.y = u1.z = u1.w = 0u; }
        if (i + 2 >= deg) { u2.x = u2.y = u2.z = u2.w = 0u; }
        if (i + 3 >= deg) { u3.x = u3.y = u3.z = u3.w = 0u; }
        ACC8(u0); ACC8(u1); ACC8(u2); ACC8(u3);
    }
    for (; i < dmax; ++i) {
        const int ii = (i < deg) ? i : last;
        uint4 u = *((const uint4*)(hsrc + (size_t)csr[beg + ii] * HDIM) + l16);
        if (i >= deg) { u.x = u.y = u.z = u.w = 0u; }
        ACC8(u);
    }
    const float inv = 1.0f / fmaxf((float)deg, 1.0f);
    uint4 o;
    o.x = packbf(a0 * inv, a1 * inv);
    o.y = packbf(a2 * inv, a3 * inv);
    o.z = packbf(a4 * inv, a5 * inv);
    o.w = packbf(a6 * inv, a7 * inv);
    ((uint4*)(agg + (size_t)g * HDIM))[l16] = o;
}

// ---------------------------------------------------------------------------
// layer-2 gather: only for the NB drug ids + NB cell ids of the batch.
// task t<NB: drug dst did[t]; t>=NB: cell dst cid[t-NB]. out agg2[t].
// ---------------------------------------------------------------------------
__global__ __launch_bounds__(256, 8)
void agg2_kernel(const u16* __restrict__ a16_d, const u16* __restrict__ a16_c,
                 const u16* __restrict__ csr_dt, const int* __restrict__ rs_c,
                 const u16* __restrict__ csr_td, const int* __restrict__ rs_d,
                 const int* __restrict__ did, const int* __restrict__ cid,
                 u16* __restrict__ agg2) {
    const int tid = threadIdx.x;
    const int lane = tid & 63;
    const int w = tid >> 6;
    const int q = lane >> 4;
    const int l16 = lane & 15;
    const int t = blockIdx.x * 16 + w * 4 + q;   // 0..2*NB-1 (grid exact)

    const bool isDrug = t < NB;
    const u16* hsrc = isDrug ? a16_c : a16_d;
    const u16* csr  = isDrug ? csr_td : csr_dt;
    const int* rs   = isDrug ? rs_d : rs_c;
    const int row   = isDrug ? did[t] : cid[t - NB];

    const int beg = rs[row];
    const int deg = rs[row + 1] - beg;
    const int last = (deg > 0) ? deg - 1 : 0;
    int dmax = deg;
    dmax = max(dmax, __shfl_xor(dmax, 16));
    dmax = max(dmax, __shfl_xor(dmax, 32));

    float a0 = 0.f, a1 = 0.f, a2 = 0.f, a3 = 0.f, a4 = 0.f, a5 = 0.f, a6 = 0.f, a7 = 0.f;
    int i = 0;
    for (; i + 3 < dmax; i += 4) {
        const int i0 = (i     < deg) ? i     : last;
        const int i1 = (i + 1 < deg) ? i + 1 : last;
        const int i2 = (i + 2 < deg) ? i + 2 : last;
        const int i3 = (i + 3 < deg) ? i + 3 : last;
        uint4 u0 = *((const uint4*)(hsrc + (size_t)csr[beg + i0] * HDIM) + l16);
        uint4 u1 = *((const uint4*)(hsrc + (size_t)csr[beg + i1] * HDIM) + l16);
        uint4 u2 = *((const uint4*)(hsrc + (size_t)csr[beg + i2] * HDIM) + l16);
        uint4 u3 = *((const uint4*)(hsrc + (size_t)csr[beg + i3] * HDIM) + l16);
        if (i     >= deg) { u0.x = u0.y = u0.z = u0.w = 0u; }
        if (i + 1 >= deg) { u1.x = u1.y = u1.z = u1.w = 0u; }
        if (i + 2 >= deg) { u2.x = u2.y = u2.z = u2.w = 0u; }
        if (i + 3 >= deg) { u3.x = u3.y = u3.z = u3.w = 0u; }
        ACC8(u0); ACC8(u1); ACC8(u2); ACC8(u3);
    }
    for (; i < dmax; ++i) {
        const int ii = (i < deg) ? i : last;
        uint4 u = *((const uint4*)(hsrc + (size_t)csr[beg + ii] * HDIM) + l16);
        if (i >= deg) { u.x = u.y = u.z = u.w = 0u; }
        ACC8(u);
    }
    const float inv = 1.0f / fmaxf((float)deg, 1.0f);
    uint4 o;
    o.x = packbf(a0 * inv, a1 * inv);
    o.y = packbf(a2 * inv, a3 * inv);
    o.z = packbf(a4 * inv, a5 * inv);
    o.w = packbf(a6 * inv, a7 * inv);
    ((uint4*)(agg2 + (size_t)t * HDIM))[l16] = o;
}

// ---------------------------------------------------------------------------
// register-blocked GEMM core: thread = 4 rows x 4 cols, WT is bf16 [k][c].
// acc written back to Xs, caller does LN.
// ---------------------------------------------------------------------------
__device__ __forceinline__ void gemm_core(float (&Xs)[32][LDA], const u16* __restrict__ WT, int tid) {
    const int cg4 = (tid & 31) * 4;      // col base
    const int rg4 = (tid >> 5) * 4;      // row base
    float acc[4][4];
#pragma unroll
    for (int r = 0; r < 4; ++r)
#pragma unroll
        for (int c = 0; c < 4; ++c) acc[r][c] = 0.f;

    for (int k4 = 0; k4 < 32; ++k4) {
        float4 xr[4];
#pragma unroll
        for (int r = 0; r < 4; ++r) xr[r] = *(const float4*)(&Xs[rg4 + r][k4 * 4]);
        float wc[4][4];  // [kk][c]
#pragma unroll
        for (int kk = 0; kk < 4; ++kk) {
            const uint2 u = *(const uint2*)(WT + (size_t)(k4 * 4 + kk) * HDIM + cg4);
            wc[kk][0] = bflo(u.x); wc[kk][1] = bfhi(u.x);
            wc[kk][2] = bflo(u.y); wc[kk][3] = bfhi(u.y);
        }
#pragma unroll
        for (int r = 0; r < 4; ++r)
#pragma unroll
            for (int c = 0; c < 4; ++c)
                acc[r][c] += xr[r].x * wc[0][c] + xr[r].y * wc[1][c]
                           + xr[r].z * wc[2][c] + xr[r].w * wc[3][c];
    }
    __syncthreads();
#pragma unroll
    for (int r = 0; r < 4; ++r)
        *(float4*)(&Xs[rg4 + r][cg4]) = make_float4(acc[r][0], acc[r][1], acc[r][2], acc[r][3]);
    __syncthreads();
}

// ---------------------------------------------------------------------------
// layer-1 GEMM + residual + LN + ReLU (full 70000 rows)
// ---------------------------------------------------------------------------
__global__ __launch_bounds__(256, 4)
void gemm_ln_kernel(const u16* __restrict__ agg,
                    const u16* __restrict__ res_d, const u16* __restrict__ res_c,
                    const u16* __restrict__ WT_dt, const u16* __restrict__ WT_td,
                    const float* __restrict__ g_c, const float* __restrict__ b_c,
                    const float* __restrict__ g_d, const float* __restrict__ b_d,
                    u16* __restrict__ o16_d, u16* __restrict__ o16_c) {
    __shared__ __align__(16) float Xs[32][LDA];

    const bool isCell = blockIdx.x < CELL_BLOCKS;
    const u16* hres = isCell ? res_c : res_d;
    const u16* WT = isCell ? WT_dt : WT_td;
    const float* g = isCell ? g_c : g_d;
    const float* b = isCell ? b_c : b_d;
    u16* o16 = isCell ? o16_c : o16_d;
    const int nrows = isCell ? NUM_CELL : NUM_DRUG;
    const int r0 = (isCell ? blockIdx.x : blockIdx.x - CELL_BLOCKS) * 32;
    const u16* aggbase = agg + (size_t)(isCell ? r0 : NUM_CELL + r0) * HDIM;

    const int tid = threadIdx.x;
    const int lane = tid & 63;
    const int w = tid >> 6;

    for (int i = tid; i < 512; i += 256) {
        const int r = i >> 4;
        const int c = i & 15;
        uint4 u = make_uint4(0u, 0u, 0u, 0u);
        if (r0 + r < nrows) u = ((const uint4*)aggbase)[i];
        *(float4*)(&Xs[r][c * 8])     = make_float4(bflo(u.x), bfhi(u.x), bflo(u.y), bfhi(u.y));
        *(float4*)(&Xs[r][c * 8 + 4]) = make_float4(bflo(u.z), bfhi(u.z), bflo(u.w), bfhi(u.w));
    }
    __syncthreads();

    gemm_core(Xs, WT, tid);

    for (int rr = 0; rr < 8; ++rr) {
        const int r = w * 8 + rr;
        const int row = r0 + r;
        if (row >= nrows) break;  // wave-uniform
        const float2 m = *(const float2*)(&Xs[r][lane * 2]);
        const u32 ur = ((const u32*)(hres + (size_t)row * HDIM))[lane];
        float t0 = bflo(ur) + m.x, t1 = bfhi(ur) + m.y;
        float s1 = t0 + t1;
        float s2 = t0 * t0 + t1 * t1;
#pragma unroll
        for (int o = 32; o; o >>= 1) {
            s1 += __shfl_xor(s1, o);
            s2 += __shfl_xor(s2, o);
        }
        const float mu = s1 * (1.0f / 128.0f);
        const float var = s2 * (1.0f / 128.0f) - mu * mu;
        const float rsq = rsqrtf(var + LN_EPS);
        const float2 gg = ((const float2*)g)[lane];
        const float2 bb = ((const float2*)b)[lane];
        const float y0 = fmaxf((t0 - mu) * rsq * gg.x + bb.x, 0.f);
        const float y1 = fmaxf((t1 - mu) * rsq * gg.y + bb.y, 0.f);
        ((u32*)(o16 + (size_t)row * HDIM))[lane] = packbf(y0, y1);
    }
}

// ---------------------------------------------------------------------------
// layer-2 GEMM + residual + LN + ReLU + final dot + sigmoid, 16 pairs/block.
// Xs rows 0-15 = drug side of pairs t0..t0+15, rows 16-31 = cell side.
// ---------------------------------------------------------------------------
__global__ __launch_bounds__(256, 4)
void l2_kernel(const u16* __restrict__ agg2,
               const u16* __restrict__ a16_d, const u16* __restrict__ a16_c,
               const int* __restrict__ did, const int* __restrict__ cid,
               const u16* __restrict__ WT_dt, const u16* __restrict__ WT_td,
               const float* __restrict__ g_c, const float* __restrict__ b_c,
               const float* __restrict__ g_d, const float* __restrict__ b_d,
               const float* __restrict__ wf, const float* __restrict__ bf_,
               float* __restrict__ out) {
    __shared__ __align__(16) float Xs[32][LDA];

    const int t0 = blockIdx.x * 16;
    const int tid = threadIdx.x;
    const int lane = tid & 63;
    const int w = tid >> 6;

    // stage: drug agg rows (pairs t0..t0+15) then cell agg rows (NB+t0..)
    for (int i = tid; i < 512; i += 256) {
        const int r = i >> 4;
        const int c = i & 15;
        const int srow = (r < 16) ? (t0 + r) : (NB + t0 + r - 16);
        const uint4 u = ((const uint4*)(agg2 + (size_t)srow * HDIM))[c];
        *(float4*)(&Xs[r][c * 8])     = make_float4(bflo(u.x), bfhi(u.x), bflo(u.y), bfhi(u.y));
        *(float4*)(&Xs[r][c * 8 + 4]) = make_float4(bflo(u.z), bfhi(u.z), bflo(u.w), bfhi(u.w));
    }
    __syncthreads();

    // GEMM: rows<16 use W_td (msg_to_drug), rows>=16 use W_dt (wave-uniform)
    const int rg4 = (tid >> 5) * 4;
    gemm_core(Xs, (rg4 < 16) ? WT_td : WT_dt, tid);

    // residual + LN + ReLU -> back into Xs as fp32
    for (int rr = 0; rr < 8; ++rr) {
        const int r = w * 8 + rr;
        const bool isDrug = r < 16;
        const int pair = t0 + (isDrug ? r : r - 16);
        const int id = isDrug ? did[pair] : cid[pair];
        const u16* hres = isDrug ? a16_d : a16_c;
        const float* g = isDrug ? g_d : g_c;
        const float* b = isDrug ? b_d : b_c;
        const float2 m = *(const float2*)(&Xs[r][lane * 2]);
        const u32 ur = ((const u32*)(hres + (size_t)id * HDIM))[lane];
        float t0f = bflo(ur) + m.x, t1f = bfhi(ur) + m.y;
        float s1 = t0f + t1f;
        float s2 = t0f * t0f + t1f * t1f;
#pragma unroll
        for (int o = 32; o; o >>= 1) {
            s1 += __shfl_xor(s1, o);
            s2 += __shfl_xor(s2, o);
        }
        const float mu = s1 * (1.0f / 128.0f);
        const float var = s2 * (1.0f / 128.0f) - mu * mu;
        const float rsq = rsqrtf(var + LN_EPS);
        const float2 gg = ((const float2*)g)[lane];
        const float2 bb = ((const float2*)b)[lane];
        Xs[r][lane * 2]     = fmaxf((t0f - mu) * rsq * gg.x + bb.x, 0.f);
        Xs[r][lane * 2 + 1] = fmaxf((t1f - mu) * rsq * gg.y + bb.y, 0.f);
    }
    __syncthreads();

    // final: wave w handles pairs w*4..w*4+3
    const float bias = bf_[0];
    for (int pr = 0; pr < 4; ++pr) {
        const int r = w * 4 + pr;  // pair index within block
        const float2 xd = *(const float2*)(&Xs[r][lane * 2]);
        const float2 xc = *(const float2*)(&Xs[16 + r][lane * 2]);
        const float2 wa = ((const float2*)wf)[lane];
        const float2 wb = ((const float2*)(wf + HDIM))[lane];
        float s = xd.x * wa.x + xd.y * wa.y + xc.x * wb.x + xc.y * wb.y;
#pragma unroll
        for (int o = 32; o; o >>= 1) s += __shfl_xor(s, o);
        if (lane == 0) out[t0 + r] = 1.0f / (1.0f + expf(-(s + bias)));
    }
}

// ---------------------------------------------------------------------------
extern "C" void kernel_launch(void* const* d_in, const int* in_sizes, int n_in,
                              void* d_out, int out_size, void* d_ws, size_t ws_size,
                              hipStream_t stream) {
    const float* emb_drug = (const float*)d_in[0];
    const float* emb_cell = (const float*)d_in[1];
    const float* W_dt     = (const float*)d_in[2];
    const float* W_td     = (const float*)d_in[3];
    const float* g_d      = (const float*)d_in[4];
    const float* b_d      = (const float*)d_in[5];
    const float* g_c      = (const float*)d_in[6];
    const float* b_c      = (const float*)d_in[7];
    const float* Wf       = (const float*)d_in[8];
    const float* bf       = (const float*)d_in[9];
    const int* dt_src     = (const int*)d_in[10];
    const int* dt_dst     = (const int*)d_in[11];
    const int* td_src     = (const int*)d_in[12];
    const int* td_dst     = (const int*)d_in[13];
    const int* drug_ids   = (const int*)d_in[14];
    const int* cell_ids   = (const int*)d_in[15];
    float* out = (float*)d_out;

    // ---- workspace layout (~57 MB) ----
    int* cnt_c  = (int*)d_ws;             // zeroed
    int* cnt_d  = cnt_c + NUM_CELL;       // zeroed
    int* cur_c  = cnt_d + NUM_DRUG;
    int* cur_d  = cur_c + NUM_CELL;
    int* rs_c   = cur_d + NUM_DRUG;
    int* rs_d   = rs_c + (NUM_CELL + 1);
    u16* csr_dt = (u16*)(rs_d + (NUM_DRUG + 1));
    u16* csr_td = csr_dt + NE;
    size_t off = ((size_t)((char*)(csr_td + NE) - (char*)d_ws) + 255) & ~(size_t)255;
    u16* e16_d = (u16*)((char*)d_ws + off);           // layer-1 tables
    u16* e16_c = e16_d + (size_t)NUM_DRUG * HDIM;
    u16* a16_d = e16_c + (size_t)NUM_CELL * HDIM;     // layer-1 outputs
    u16* a16_c = a16_d + (size_t)NUM_DRUG * HDIM;
    u16* agg16 = a16_c + (size_t)NUM_CELL * HDIM;     // 70000-row agg buffer
    u16* wdt16 = agg16 + (size_t)NUM_TOT * HDIM;      // WT_dt bf16 [k][c]
    u16* wtd16 = wdt16 + HDIM * HDIM;                 // WT_td bf16 [k][c]
    u16* agg2  = agg16;                               // alias: agg16 dead after gemm_ln1

    const dim3 B(256);
    const int gemm_blocks = CELL_BLOCKS + DRUG_BLOCKS;

    // ---- build CSR + bf16 casts ----
    hipMemsetAsync(d_ws, 0, (size_t)(NUM_CELL + NUM_DRUG) * sizeof(int), stream);
    prep_kernel<<<CAST_BLOCKS + WCAST_BLOCKS + HIST_BLOCKS, B, 0, stream>>>(
        emb_drug, emb_cell, e16_d, e16_c, W_dt, W_td, wdt16, wtd16,
        dt_dst, td_dst, cnt_c, cnt_d);
    scan_kernel<<<2, 1024, 0, stream>>>(cnt_c, rs_c, cur_c, NUM_CELL, cnt_d, rs_d, cur_d, NUM_DRUG);
    fill_kernel<<<FILL_BLOCKS, B, 0, stream>>>(dt_src, dt_dst, td_src, td_dst,
                                               cur_c, cur_d, csr_dt, csr_td);

    // ---- layer 1 (full) ----
    agg_kernel<<<AGG_BLOCKS, B, 0, stream>>>(e16_d, e16_c, csr_dt, rs_c, csr_td, rs_d, agg16);
    gemm_ln_kernel<<<gemm_blocks, B, 0, stream>>>(agg16, e16_d, e16_c,
                                                  wdt16, wtd16, g_c, b_c, g_d, b_d,
                                                  a16_d, a16_c);
    // ---- layer 2 (batch rows only) ----
    agg2_kernel<<<(2 * NB) / 16, B, 0, stream>>>(a16_d, a16_c, csr_dt, rs_c, csr_td, rs_d,
                                                 drug_ids, cell_ids, agg2);
    l2_kernel<<<NB / 16, B, 0, stream>>>(agg2, a16_d, a16_c, drug_ids, cell_ids,
                                         wdt16, wtd16, g_c, b_c, g_d, b_d, Wf, bf, out);
}

// Round 12
// 357.856 us; speedup vs baseline: 1.1096x; 1.1096x over previous
//
#include <hip/hip_runtime.h>
#include <math.h>

#define NUM_DRUG 50000
#define NUM_CELL 20000
#define NUM_TOT  (NUM_DRUG + NUM_CELL)
#define HDIM 128
#define NE 600000
#define NB 4096
#define LN_EPS 1e-5f
#define LDAB 136  // padded bf16 LDS row (u16 elems): 272B stride -> 2-way bank alias (free)
#define LDAM 132  // padded fp32 LDS row

#define CELL_BLOCKS ((NUM_CELL + 31) / 32)      // 625
#define DRUG_BLOCKS ((NUM_DRUG + 31) / 32)      // 1563
#define AGG_BLOCKS  (NUM_TOT / 16)              // 4375 (exact)
#define CAST_BLOCKS (NUM_TOT * HDIM / 8 / 256)  // 4375
#define WCAST_BLOCKS 16                         // 2*128*128/8/256
#define EPACK_BLOCKS ((2 * NE / 8 + 255) / 256) // 586
#define HIST_BLOCKS ((2 * NE + 255) / 256)      // 4688
#define FILL_BLOCKS 2048                        // 8 partitions x 256 blocks

typedef unsigned short u16;
typedef unsigned int u32;
typedef __attribute__((ext_vector_type(8))) short bf16x8;
typedef __attribute__((ext_vector_type(4))) float f32x4;

__device__ __forceinline__ float bflo(u32 u) { return __uint_as_float(u << 16); }
__device__ __forceinline__ float bfhi(u32 u) { return __uint_as_float(u & 0xFFFF0000u); }
__device__ __forceinline__ u32 f2bf1(float f) {
    u32 u = __float_as_uint(f);
    return (u + 0x7FFFu + ((u >> 16) & 1u)) >> 16;  // RNE
}
__device__ __forceinline__ u32 packbf(float lo, float hi) {
    return f2bf1(lo) | (f2bf1(hi) << 16);
}

#define ACC8(u) do { \
    a0 += bflo((u).x); a1 += bfhi((u).x); a2 += bflo((u).y); a3 += bfhi((u).y); \
    a4 += bflo((u).z); a5 += bfhi((u).z); a6 += bflo((u).w); a7 += bfhi((u).w); } while (0)

// ---------------------------------------------------------------------------
// prep: [0,CAST) cast emb fp32->bf16; [CAST,+W) cast W fp32->bf16 (no
// transpose, [out][in]); [+W,+EPACK) pack edges dst<<16|src; rest: histogram
// ---------------------------------------------------------------------------
__global__ void prep_kernel(const float* __restrict__ ed, const float* __restrict__ ec,
                            u16* __restrict__ e16d, u16* __restrict__ e16c,
                            const float* __restrict__ W_dt, const float* __restrict__ W_td,
                            u16* __restrict__ w16dt, u16* __restrict__ w16td,
                            const int* __restrict__ dt_src, const int* __restrict__ dt_dst,
                            const int* __restrict__ td_src, const int* __restrict__ td_dst,
                            u32* __restrict__ ep_dt, u32* __restrict__ ep_td,
                            int* __restrict__ cnt_c, int* __restrict__ cnt_d) {
    if (blockIdx.x < CAST_BLOCKS) {
        const int ND8 = NUM_DRUG * HDIM / 8;
        int t = blockIdx.x * blockDim.x + threadIdx.x;
        const float4* src;
        u16* dst;
        int i;
        if (t < ND8) { src = (const float4*)ed; dst = e16d; i = t; }
        else { src = (const float4*)ec; dst = e16c; i = t - ND8; }
        float4 v0 = src[2 * i], v1 = src[2 * i + 1];
        uint4 o;
        o.x = packbf(v0.x, v0.y);
        o.y = packbf(v0.z, v0.w);
        o.z = packbf(v1.x, v1.y);
        o.w = packbf(v1.z, v1.w);
        ((uint4*)dst)[i] = o;
    } else if (blockIdx.x < CAST_BLOCKS + WCAST_BLOCKS) {
        int t = (blockIdx.x - CAST_BLOCKS) * blockDim.x + threadIdx.x;  // 0..4095
        const float* Wsrc = (t < 2048) ? W_dt : W_td;
        u16* Wdst = (t < 2048) ? w16dt : w16td;
        const int i = t & 2047;
        float4 v0 = ((const float4*)Wsrc)[2 * i], v1 = ((const float4*)Wsrc)[2 * i + 1];
        uint4 o;
        o.x = packbf(v0.x, v0.y);
        o.y = packbf(v0.z, v0.w);
        o.z = packbf(v1.x, v1.y);
        o.w = packbf(v1.z, v1.w);
        ((uint4*)Wdst)[i] = o;
    } else if (blockIdx.x < CAST_BLOCKS + WCAST_BLOCKS + EPACK_BLOCKS) {
        int t = (blockIdx.x - CAST_BLOCKS - WCAST_BLOCKS) * blockDim.x + threadIdx.x;
        if (t < 2 * NE / 8) {
            const bool isdt = t < NE / 8;
            const int t8 = isdt ? t : t - NE / 8;
            const int4* src = (const int4*)(isdt ? dt_src : td_src);
            const int4* dst = (const int4*)(isdt ? dt_dst : td_dst);
            u32* ep = isdt ? ep_dt : ep_td;
            const int4 sa = src[2 * t8], sb = src[2 * t8 + 1];
            const int4 da = dst[2 * t8], db = dst[2 * t8 + 1];
            uint4 o1, o2;
            o1.x = ((u32)da.x << 16) | (u32)sa.x;
            o1.y = ((u32)da.y << 16) | (u32)sa.y;
            o1.z = ((u32)da.z << 16) | (u32)sa.z;
            o1.w = ((u32)da.w << 16) | (u32)sa.w;
            o2.x = ((u32)db.x << 16) | (u32)sb.x;
            o2.y = ((u32)db.y << 16) | (u32)sb.y;
            o2.z = ((u32)db.z << 16) | (u32)sb.z;
            o2.w = ((u32)db.w << 16) | (u32)sb.w;
            ((uint4*)ep)[2 * t8] = o1;
            ((uint4*)ep)[2 * t8 + 1] = o2;
        }
    } else {
        int t = (blockIdx.x - CAST_BLOCKS - WCAST_BLOCKS - EPACK_BLOCKS) * blockDim.x + threadIdx.x;
        if (t < NE) {
            atomicAdd(&cnt_c[dt_dst[t]], 1);
        } else if (t < 2 * NE) {
            atomicAdd(&cnt_d[td_dst[t - NE]], 1);
        }
    }
}

// ---------------------------------------------------------------------------
// single-block exclusive scan; writes rs (n+1) and cur (=rs copy)
// ---------------------------------------------------------------------------
__global__ void scan_kernel(const int* __restrict__ cnt0, int* __restrict__ rs0, int* __restrict__ cur0, int n0,
                            const int* __restrict__ cnt1, int* __restrict__ rs1, int* __restrict__ cur1, int n1) {
    const int* cnt = blockIdx.x ? cnt1 : cnt0;
    int* rs  = blockIdx.x ? rs1 : rs0;
    int* cur = blockIdx.x ? cur1 : cur0;
    int n = blockIdx.x ? n1 : n0;

    __shared__ int wsum[16];
    __shared__ int s_carry;
    const int tid = threadIdx.x;
    const int lane = tid & 63;
    const int w = tid >> 6;
    if (tid == 0) s_carry = 0;
    __syncthreads();

    for (int base = 0; base < n; base += 1024) {
        int v = (base + tid < n) ? cnt[base + tid] : 0;
        int x = v;
#pragma unroll
        for (int o = 1; o < 64; o <<= 1) {
            int y = __shfl_up(x, o);
            if (lane >= o) x += y;
        }
        if (lane == 63) wsum[w] = x;
        __syncthreads();
        if (w == 0 && lane < 16) {
            int y = wsum[lane];
#pragma unroll
            for (int o = 1; o < 16; o <<= 1) {
                int z = __shfl_up(y, o);
                if (lane >= o) y += z;
            }
            wsum[lane] = y;
        }
        __syncthreads();
        int total = wsum[15];
        int excl = s_carry + (w ? wsum[w - 1] : 0) + x - v;
        if (base + tid < n) { rs[base + tid] = excl; cur[base + tid] = excl; }
        __syncthreads();
        if (tid == 0) s_carry += total;
        __syncthreads();
    }
    if (tid == 0) rs[n] = s_carry;
}

// ---------------------------------------------------------------------------
// XCD-partitioned fill from packed edges: partition p = blockIdx&7 owns a
// contiguous dst range; its CSR slice stays in one XCD's L2.
// ---------------------------------------------------------------------------
__global__ __launch_bounds__(256, 8)
void fill_kernel(const u32* __restrict__ ep_dt, const u32* __restrict__ ep_td,
                 int* __restrict__ cur_c, int* __restrict__ cur_d,
                 u16* __restrict__ csr_dt, u16* __restrict__ csr_td) {
    const int p = blockIdx.x & 7;
    const int stride = (FILL_BLOCKS >> 3) * 256;      // 65536
    const int base = (blockIdx.x >> 3) * 256 + threadIdx.x;
    const int clo = p * (NUM_CELL / 8);
    const int dlo = p * (NUM_DRUG / 8);

    for (int t = base; t < NE; t += stride) {
        const u32 e = ep_dt[t];
        const int d = (int)(e >> 16);
        if ((unsigned)(d - clo) < (unsigned)(NUM_CELL / 8)) {
            const int pos = atomicAdd(&cur_c[d], 1);
            csr_dt[pos] = (u16)e;
        }
    }
    for (int t = base; t < NE; t += stride) {
        const u32 e = ep_td[t];
        const int d = (int)(e >> 16);
        if ((unsigned)(d - dlo) < (unsigned)(NUM_DRUG / 8)) {
            const int pos = atomicAdd(&cur_d[d], 1);
            csr_td[pos] = (u16)e;
        }
    }
}

// ---------------------------------------------------------------------------
// layer-1 gather: quarter-wave owns one dst row, unroll-4, zero LDS.
// ---------------------------------------------------------------------------
__global__ __launch_bounds__(256, 8)
void agg_kernel(const u16* __restrict__ srcd, const u16* __restrict__ srcc,
                const u16* __restrict__ csr_dt, const int* __restrict__ rs_c,
                const u16* __restrict__ csr_td, const int* __restrict__ rs_d,
                u16* __restrict__ agg) {
    const int tid = threadIdx.x;
    const int lane = tid & 63;
    const int w = tid >> 6;
    const int q = lane >> 4;
    const int l16 = lane & 15;
    const int g = blockIdx.x * 16 + w * 4 + q;   // 0..NUM_TOT-1 (grid exact)

    const bool isCell = g < NUM_CELL;
    const u16* hsrc = isCell ? srcd : srcc;
    const u16* csr  = isCell ? csr_dt : csr_td;
    const int* rs   = isCell ? rs_c : rs_d;
    const int row   = isCell ? g : g - NUM_CELL;

    const int beg = rs[row];
    const int deg = rs[row + 1] - beg;
    const int last = (deg > 0) ? deg - 1 : 0;
    int dmax = deg;
    dmax = max(dmax, __shfl_xor(dmax, 16));
    dmax = max(dmax, __shfl_xor(dmax, 32));

    float a0 = 0.f, a1 = 0.f, a2 = 0.f, a3 = 0.f, a4 = 0.f, a5 = 0.f, a6 = 0.f, a7 = 0.f;
    int i = 0;
    for (; i + 3 < dmax; i += 4) {
        const int i0 = (i     < deg) ? i     : last;
        const int i1 = (i + 1 < deg) ? i + 1 : last;
        const int i2 = (i + 2 < deg) ? i + 2 : last;
        const int i3 = (i + 3 < deg) ? i + 3 : last;
        uint4 u0 = *((const uint4*)(hsrc + (size_t)csr[beg + i0] * HDIM) + l16);
        uint4 u1 = *((const uint4*)(hsrc + (size_t)csr[beg + i1] * HDIM) + l16);
        uint4 u2 = *((const uint4*)(hsrc + (size_t)csr[beg + i2] * HDIM) + l16);
        uint4 u3 = *((const uint4*)(hsrc + (size_t)csr[beg + i3] * HDIM) + l16);
        if (i     >= deg) { u0.x = u0.y = u0.z = u0.w = 0u; }
        if (i + 1 >= deg) { u1.x = u1.y = u1.z = u1.w = 0u; }
        if (i + 2 >= deg) { u2.x = u2.y = u2.z = u2.w = 0u; }
        if (i + 3 >= deg) { u3.x = u3.y = u3.z = u3.w = 0u; }
        ACC8(u0); ACC8(u1); ACC8(u2); ACC8(u3);
    }
    for (; i < dmax; ++i) {
        const int ii = (i < deg) ? i : last;
        uint4 u = *((const uint4*)(hsrc + (size_t)csr[beg + ii] * HDIM) + l16);
        if (i >= deg) { u.x = u.y = u.z = u.w = 0u; }
        ACC8(u);
    }
    const float inv = 1.0f / fmaxf((float)deg, 1.0f);
    uint4 o;
    o.x = packbf(a0 * inv, a1 * inv);
    o.y = packbf(a2 * inv, a3 * inv);
    o.z = packbf(a4 * inv, a5 * inv);
    o.w = packbf(a6 * inv, a7 * inv);
    ((uint4*)(agg + (size_t)g * HDIM))[l16] = o;
}

// ---------------------------------------------------------------------------
// layer-2 gather (batch rows only)
// ---------------------------------------------------------------------------
__global__ __launch_bounds__(256, 8)
void agg2_kernel(const u16* __restrict__ a16_d, const u16* __restrict__ a16_c,
                 const u16* __restrict__ csr_dt, const int* __restrict__ rs_c,
                 const u16* __restrict__ csr_td, const int* __restrict__ rs_d,
                 const int* __restrict__ did, const int* __restrict__ cid,
                 u16* __restrict__ agg2) {
    const int tid = threadIdx.x;
    const int lane = tid & 63;
    const int w = tid >> 6;
    const int q = lane >> 4;
    const int l16 = lane & 15;
    const int t = blockIdx.x * 16 + w * 4 + q;   // 0..2*NB-1 (grid exact)

    const bool isDrug = t < NB;
    const u16* hsrc = isDrug ? a16_c : a16_d;
    const u16* csr  = isDrug ? csr_td : csr_dt;
    const int* rs   = isDrug ? rs_d : rs_c;
    const int row   = isDrug ? did[t] : cid[t - NB];

    const int beg = rs[row];
    const int deg = rs[row + 1] - beg;
    const int last = (deg > 0) ? deg - 1 : 0;
    int dmax = deg;
    dmax = max(dmax, __shfl_xor(dmax, 16));
    dmax = max(dmax, __shfl_xor(dmax, 32));

    float a0 = 0.f, a1 = 0.f, a2 = 0.f, a3 = 0.f, a4 = 0.f, a5 = 0.f, a6 = 0.f, a7 = 0.f;
    int i = 0;
    for (; i + 3 < dmax; i += 4) {
        const int i0 = (i     < deg) ? i     : last;
        const int i1 = (i + 1 < deg) ? i + 1 : last;
        const int i2 = (i + 2 < deg) ? i + 2 : last;
        const int i3 = (i + 3 < deg) ? i + 3 : last;
        uint4 u0 = *((const uint4*)(hsrc + (size_t)csr[beg + i0] * HDIM) + l16);
        uint4 u1 = *((const uint4*)(hsrc + (size_t)csr[beg + i1] * HDIM) + l16);
        uint4 u2 = *((const uint4*)(hsrc + (size_t)csr[beg + i2] * HDIM) + l16);
        uint4 u3 = *((const uint4*)(hsrc + (size_t)csr[beg + i3] * HDIM) + l16);
        if (i     >= deg) { u0.x = u0.y = u0.z = u0.w = 0u; }
        if (i + 1 >= deg) { u1.x = u1.y = u1.z = u1.w = 0u; }
        if (i + 2 >= deg) { u2.x = u2.y = u2.z = u2.w = 0u; }
        if (i + 3 >= deg) { u3.x = u3.y = u3.z = u3.w = 0u; }
        ACC8(u0); ACC8(u1); ACC8(u2); ACC8(u3);
    }
    for (; i < dmax; ++i) {
        const int ii = (i < deg) ? i : last;
        uint4 u = *((const uint4*)(hsrc + (size_t)csr[beg + ii] * HDIM) + l16);
        if (i >= deg) { u.x = u.y = u.z = u.w = 0u; }
        ACC8(u);
    }
    const float inv = 1.0f / fmaxf((float)deg, 1.0f);
    uint4 o;
    o.x = packbf(a0 * inv, a1 * inv);
    o.y = packbf(a2 * inv, a3 * inv);
    o.z = packbf(a4 * inv, a5 * inv);
    o.w = packbf(a6 * inv, a7 * inv);
    ((uint4*)(agg2 + (size_t)t * HDIM))[l16] = o;
}

// ---------------------------------------------------------------------------
// MFMA GEMM core: 32x128 = X(32x128,bf16 LDS) @ W^T, W bf16 [out][in] global.
// Wave w: mt=w&1 (16 rows), nt in [(w>>1)*4, +4) (64 cols). 16 MFMAs/wave of
// v_mfma_f32_16x16x32_bf16. A: row=lane&15, k=(lane>>4)*8+j. B[k][n]=W[n][k]:
// col=lane&15, same k chunking -> 16B contiguous from W row `col`.
// D (m89-verified): col=lane&15, row=(lane>>4)*4+reg. Result -> Ms fp32 LDS.
// ---------------------------------------------------------------------------
__device__ __forceinline__ void mfma_core(const u16* __restrict__ Xs16, float* __restrict__ Ms,
                                          const u16* __restrict__ Wmt0, const u16* __restrict__ Wmt1,
                                          int tid) {
    const int lane = tid & 63;
    const int w = tid >> 6;
    const int mt = w & 1;
    const int ntb = (w >> 1) * 4;
    const int l15 = lane & 15;
    const int kg = lane >> 4;
    const u16* W16 = mt ? Wmt1 : Wmt0;

    f32x4 acc[4];
#pragma unroll
    for (int nt = 0; nt < 4; ++nt) acc[nt] = (f32x4){0.f, 0.f, 0.f, 0.f};

#pragma unroll
    for (int ks = 0; ks < 4; ++ks) {
        const bf16x8 a = *(const bf16x8*)(Xs16 + (mt * 16 + l15) * LDAB + ks * 32 + kg * 8);
#pragma unroll
        for (int nt = 0; nt < 4; ++nt) {
            const int col = (ntb + nt) * 16 + l15;
            const bf16x8 b = *(const bf16x8*)(W16 + (size_t)col * HDIM + ks * 32 + kg * 8);
            acc[nt] = __builtin_amdgcn_mfma_f32_16x16x32_bf16(a, b, acc[nt], 0, 0, 0);
        }
    }
#pragma unroll
    for (int nt = 0; nt < 4; ++nt)
#pragma unroll
        for (int r = 0; r < 4; ++r)
            Ms[(mt * 16 + kg * 4 + r) * LDAM + (ntb + nt) * 16 + l15] = acc[nt][r];
}

// ---------------------------------------------------------------------------
// layer-1 MFMA GEMM + residual + LN + ReLU (full 70000 rows)
// ---------------------------------------------------------------------------
__global__ __launch_bounds__(256, 6)
void gemm_ln_kernel(const u16* __restrict__ agg,
                    const u16* __restrict__ res_d, const u16* __restrict__ res_c,
                    const u16* __restrict__ w16dt, const u16* __restrict__ w16td,
                    const float* __restrict__ g_c, const float* __restrict__ b_c,
                    const float* __restrict__ g_d, const float* __restrict__ b_d,
                    u16* __restrict__ o16_d, u16* __restrict__ o16_c) {
    __shared__ __align__(16) u16 Xs16[32 * LDAB];
    __shared__ __align__(16) float Ms[32 * LDAM];

    const bool isCell = blockIdx.x < CELL_BLOCKS;
    const u16* hres = isCell ? res_c : res_d;
    const u16* W16 = isCell ? w16dt : w16td;
    const float* g = isCell ? g_c : g_d;
    const float* b = isCell ? b_c : b_d;
    u16* o16 = isCell ? o16_c : o16_d;
    const int nrows = isCell ? NUM_CELL : NUM_DRUG;
    const int r0 = (isCell ? blockIdx.x : blockIdx.x - CELL_BLOCKS) * 32;
    const u16* aggbase = agg + (size_t)(isCell ? r0 : NUM_CELL + r0) * HDIM;

    const int tid = threadIdx.x;
    const int lane = tid & 63;
    const int w = tid >> 6;

    // stage bf16 tile (pad LDAB)
    for (int i = tid; i < 512; i += 256) {
        const int r = i >> 4;
        const int c = i & 15;
        uint4 u = make_uint4(0u, 0u, 0u, 0u);
        if (r0 + r < nrows) u = ((const uint4*)aggbase)[i];
        *(uint4*)(Xs16 + r * LDAB + c * 8) = u;
    }
    __syncthreads();

    mfma_core(Xs16, Ms, W16, W16, tid);
    __syncthreads();

    // residual(bf16) + LN + ReLU -> bf16 out
    for (int rr = 0; rr < 8; ++rr) {
        const int r = w * 8 + rr;
        const int row = r0 + r;
        if (row >= nrows) break;  // wave-uniform
        const float2 m = *(const float2*)(Ms + r * LDAM + lane * 2);
        const u32 ur = ((const u32*)(hres + (size_t)row * HDIM))[lane];
        float t0 = bflo(ur) + m.x, t1 = bfhi(ur) + m.y;
        float s1 = t0 + t1;
        float s2 = t0 * t0 + t1 * t1;
#pragma unroll
        for (int o = 32; o; o >>= 1) {
            s1 += __shfl_xor(s1, o);
            s2 += __shfl_xor(s2, o);
        }
        const float mu = s1 * (1.0f / 128.0f);
        const float var = s2 * (1.0f / 128.0f) - mu * mu;
        const float rsq = rsqrtf(var + LN_EPS);
        const float2 gg = ((const float2*)g)[lane];
        const float2 bb = ((const float2*)b)[lane];
        const float y0 = fmaxf((t0 - mu) * rsq * gg.x + bb.x, 0.f);
        const float y1 = fmaxf((t1 - mu) * rsq * gg.y + bb.y, 0.f);
        ((u32*)(o16 + (size_t)row * HDIM))[lane] = packbf(y0, y1);
    }
}

// ---------------------------------------------------------------------------
// layer-2 MFMA GEMM + residual + LN + ReLU + final dot + sigmoid, 16 pairs/blk
// rows 0-15 = drug side (W_td), rows 16-31 = cell side (W_dt); mt-uniform.
// ---------------------------------------------------------------------------
__global__ __launch_bounds__(256, 6)
void l2_kernel(const u16* __restrict__ agg2,
               const u16* __restrict__ a16_d, const u16* __restrict__ a16_c,
               const int* __restrict__ did, const int* __restrict__ cid,
               const u16* __restrict__ w16dt, const u16* __restrict__ w16td,
               const float* __restrict__ g_c, const float* __restrict__ b_c,
               const float* __restrict__ g_d, const float* __restrict__ b_d,
               const float* __restrict__ wf, const float* __restrict__ bf_,
               float* __restrict__ out) {
    __shared__ __align__(16) u16 Xs16[32 * LDAB];
    __shared__ __align__(16) float Ms[32 * LDAM];

    const int t0 = blockIdx.x * 16;
    const int tid = threadIdx.x;
    const int lane = tid & 63;
    const int w = tid >> 6;

    for (int i = tid; i < 512; i += 256) {
        const int r = i >> 4;
        const int c = i & 15;
        const int srow = (r < 16) ? (t0 + r) : (NB + t0 + r - 16);
        const uint4 u = ((const uint4*)(agg2 + (size_t)srow * HDIM))[c];
        *(uint4*)(Xs16 + r * LDAB + c * 8) = u;
    }
    __syncthreads();

    mfma_core(Xs16, Ms, w16td, w16dt, tid);  // mt0 (drug) uses W_td, mt1 W_dt
    __syncthreads();

    for (int rr = 0; rr < 8; ++rr) {
        const int r = w * 8 + rr;
        const bool isDrug = r < 16;
        const int pair = t0 + (isDrug ? r : r - 16);
        const int id = isDrug ? did[pair] : cid[pair];
        const u16* hres = isDrug ? a16_d : a16_c;
        const float* g = isDrug ? g_d : g_c;
        const float* b = isDrug ? b_d : b_c;
        const float2 m = *(const float2*)(Ms + r * LDAM + lane * 2);
        const u32 ur = ((const u32*)(hres + (size_t)id * HDIM))[lane];
        float t0f = bflo(ur) + m.x, t1f = bfhi(ur) + m.y;
        float s1 = t0f + t1f;
        float s2 = t0f * t0f + t1f * t1f;
#pragma unroll
        for (int o = 32; o; o >>= 1) {
            s1 += __shfl_xor(s1, o);
            s2 += __shfl_xor(s2, o);
        }
        const float mu = s1 * (1.0f / 128.0f);
        const float var = s2 * (1.0f / 128.0f) - mu * mu;
        const float rsq = rsqrtf(var + LN_EPS);
        const float2 gg = ((const float2*)g)[lane];
        const float2 bb = ((const float2*)b)[lane];
        Ms[r * LDAM + lane * 2]     = fmaxf((t0f - mu) * rsq * gg.x + bb.x, 0.f);
        Ms[r * LDAM + lane * 2 + 1] = fmaxf((t1f - mu) * rsq * gg.y + bb.y, 0.f);
    }
    __syncthreads();

    const float bias = bf_[0];
    for (int pr = 0; pr < 4; ++pr) {
        const int r = w * 4 + pr;
        const float2 xd = *(const float2*)(Ms + r * LDAM + lane * 2);
        const float2 xc = *(const float2*)(Ms + (16 + r) * LDAM + lane * 2);
        const float2 wa = ((const float2*)wf)[lane];
        const float2 wb = ((const float2*)(wf + HDIM))[lane];
        float s = xd.x * wa.x + xd.y * wa.y + xc.x * wb.x + xc.y * wb.y;
#pragma unroll
        for (int o = 32; o; o >>= 1) s += __shfl_xor(s, o);
        if (lane == 0) out[t0 + r] = 1.0f / (1.0f + expf(-(s + bias)));
    }
}

// ---------------------------------------------------------------------------
extern "C" void kernel_launch(void* const* d_in, const int* in_sizes, int n_in,
                              void* d_out, int out_size, void* d_ws, size_t ws_size,
                              hipStream_t stream) {
    const float* emb_drug = (const float*)d_in[0];
    const float* emb_cell = (const float*)d_in[1];
    const float* W_dt     = (const float*)d_in[2];
    const float* W_td     = (const float*)d_in[3];
    const float* g_d      = (const float*)d_in[4];
    const float* b_d      = (const float*)d_in[5];
    const float* g_c      = (const float*)d_in[6];
    const float* b_c      = (const float*)d_in[7];
    const float* Wf       = (const float*)d_in[8];
    const float* bf       = (const float*)d_in[9];
    const int* dt_src     = (const int*)d_in[10];
    const int* dt_dst     = (const int*)d_in[11];
    const int* td_src     = (const int*)d_in[12];
    const int* td_dst     = (const int*)d_in[13];
    const int* drug_ids   = (const int*)d_in[14];
    const int* cell_ids   = (const int*)d_in[15];
    float* out = (float*)d_out;

    // ---- workspace layout (~62 MB) ----
    int* cnt_c  = (int*)d_ws;             // zeroed
    int* cnt_d  = cnt_c + NUM_CELL;       // zeroed
    int* cur_c  = cnt_d + NUM_DRUG;
    int* cur_d  = cur_c + NUM_CELL;
    int* rs_c   = cur_d + NUM_DRUG;
    int* rs_d   = rs_c + (NUM_CELL + 1);
    u16* csr_dt = (u16*)(rs_d + (NUM_DRUG + 1));
    u16* csr_td = csr_dt + NE;
    size_t offe = ((size_t)((char*)(csr_td + NE) - (char*)d_ws) + 255) & ~(size_t)255;
    u32* ep_dt  = (u32*)((char*)d_ws + offe);
    u32* ep_td  = ep_dt + NE;
    u16* e16_d  = (u16*)(ep_td + NE);                 // layer-1 tables
    u16* e16_c  = e16_d + (size_t)NUM_DRUG * HDIM;
    u16* a16_d  = e16_c + (size_t)NUM_CELL * HDIM;    // layer-1 outputs
    u16* a16_c  = a16_d + (size_t)NUM_DRUG * HDIM;
    u16* agg16  = a16_c + (size_t)NUM_CELL * HDIM;    // 70000-row agg buffer
    u16* w16dt  = agg16 + (size_t)NUM_TOT * HDIM;     // W_dt bf16 [out][in]
    u16* w16td  = w16dt + HDIM * HDIM;                // W_td bf16 [out][in]
    u16* agg2   = agg16;                              // alias: dead after gemm_ln1

    const dim3 B(256);
    const int gemm_blocks = CELL_BLOCKS + DRUG_BLOCKS;

    // ---- build CSR + bf16 casts + edge packing ----
    hipMemsetAsync(d_ws, 0, (size_t)(NUM_CELL + NUM_DRUG) * sizeof(int), stream);
    prep_kernel<<<CAST_BLOCKS + WCAST_BLOCKS + EPACK_BLOCKS + HIST_BLOCKS, B, 0, stream>>>(
        emb_drug, emb_cell, e16_d, e16_c, W_dt, W_td, w16dt, w16td,
        dt_src, dt_dst, td_src, td_dst, ep_dt, ep_td, cnt_c, cnt_d);
    scan_kernel<<<2, 1024, 0, stream>>>(cnt_c, rs_c, cur_c, NUM_CELL, cnt_d, rs_d, cur_d, NUM_DRUG);
    fill_kernel<<<FILL_BLOCKS, B, 0, stream>>>(ep_dt, ep_td, cur_c, cur_d, csr_dt, csr_td);

    // ---- layer 1 (full) ----
    agg_kernel<<<AGG_BLOCKS, B, 0, stream>>>(e16_d, e16_c, csr_dt, rs_c, csr_td, rs_d, agg16);
    gemm_ln_kernel<<<gemm_blocks, B, 0, stream>>>(agg16, e16_d, e16_c,
                                                  w16dt, w16td, g_c, b_c, g_d, b_d,
                                                  a16_d, a16_c);
    // ---- layer 2 (batch rows only) ----
    agg2_kernel<<<(2 * NB) / 16, B, 0, stream>>>(a16_d, a16_c, csr_dt, rs_c, csr_td, rs_d,
                                                 drug_ids, cell_ids, agg2);
    l2_kernel<<<NB / 16, B, 0, stream>>>(agg2, a16_d, a16_c, drug_ids, cell_ids,
                                         w16dt, w16td, g_c, b_c, g_d, b_d, Wf, bf, out);
}